// Round 1
// baseline (1657.483 us; speedup 1.0000x reference)
//
#include <hip/hip_runtime.h>
#include <stdint.h>
#include <stddef.h>
#include <vector>
#include <algorithm>
#include <utility>

// Problem constants (B=2, L=4096, D=256, H=8, K=sqrt(L)=64, 10 Lloyd iters)
#define NPTS 8192
#define DIM  256
#define KC   64
#define LSEQ 4096
#define NB   2
#define KM_ITERS 10
#define NCHUNK 64   // 8192/128 points per chunk

// JAX threefry mode: 1 = partitionable (default since jax 0.4.36), 0 = original
#define JAX_THREEFRY_PARTITIONABLE 1

// ---------------- static device scratch (fully rewritten every call) --------
__device__ float g_R[NPTS * DIM];          // 8 MB   rotated points
__device__ float g_xsq[NPTS];              // 32 KB  per-point squared norm
__device__ float g_cent[KC * DIM];         // 64 KB  centroids
__device__ float g_csq[KC];                // per-centroid squared norm
__device__ int   g_idx[NPTS];              // assignments (final = cid)
__device__ float g_part[NCHUNK][KC][DIM];  // 4 MB   chunked segment sums
__device__ int   g_pcnt[NCHUNK][KC];       // chunked counts

// ---------------- host threefry2x32 (exact JAX semantics) -------------------
static inline uint32_t rotl32(uint32_t x, int r) { return (x << r) | (x >> (32 - r)); }

static void threefry2x32(uint32_t k0, uint32_t k1, uint32_t x0, uint32_t x1,
                         uint32_t& o0, uint32_t& o1) {
  const uint32_t ks0 = k0, ks1 = k1, ks2 = k0 ^ k1 ^ 0x1BD11BDAu;
  const int r1[4] = {13, 15, 26, 6}, r2[4] = {17, 29, 16, 24};
  x0 += ks0; x1 += ks1;
  for (int i = 0; i < 4; ++i) { x0 += x1; x1 = rotl32(x1, r1[i]); x1 ^= x0; }
  x0 += ks1; x1 += ks2 + 1u;
  for (int i = 0; i < 4; ++i) { x0 += x1; x1 = rotl32(x1, r2[i]); x1 ^= x0; }
  x0 += ks2; x1 += ks0 + 2u;
  for (int i = 0; i < 4; ++i) { x0 += x1; x1 = rotl32(x1, r1[i]); x1 ^= x0; }
  x0 += ks0; x1 += ks1 + 3u;
  for (int i = 0; i < 4; ++i) { x0 += x1; x1 = rotl32(x1, r2[i]); x1 ^= x0; }
  x0 += ks1; x1 += ks2 + 4u;
  for (int i = 0; i < 4; ++i) { x0 += x1; x1 = rotl32(x1, r1[i]); x1 ^= x0; }
  x0 += ks2; x1 += ks0 + 5u;
  o0 = x0; o1 = x1;
}

struct InitIdx { int v[KC]; };

// jax.random.choice(key(42), 8192, (64,), replace=False)
//  = permutation(key, arange(8192))[:64]
//  = _shuffle: 2 rounds of {key,sub = split(key); bits = random_bits(sub,32,(N,));
//                           stable sort_key_val(bits, vals)}
static InitIdx compute_init_indices() {
  uint32_t k0 = 0u, k1 = 42u;  // jax.random.key(42) -> [0, 42]
  std::vector<int> val(NPTS);
  for (int i = 0; i < NPTS; ++i) val[i] = i;
  std::vector<std::pair<uint32_t, int>> kv(NPTS);
  for (int round = 0; round < 2; ++round) {
    uint32_t nk0, nk1, sk0, sk1;
#if JAX_THREEFRY_PARTITIONABLE
    // split: keys[i] = threefry(key, (0, i)) full 2-word output
    threefry2x32(k0, k1, 0u, 0u, nk0, nk1);
    threefry2x32(k0, k1, 0u, 1u, sk0, sk1);
    k0 = nk0; k1 = nk1;
    // bits[i] = xor-fold of threefry(subkey, (0, i))
    for (int i = 0; i < NPTS; ++i) {
      uint32_t o0, o1;
      threefry2x32(sk0, sk1, 0u, (uint32_t)i, o0, o1);
      kv[i] = std::make_pair(o0 ^ o1, val[i]);
    }
#else
    // original: split via counts [0,1,2,3] paired as (0,2),(1,3)
    uint32_t a0, a1, b0, b1;
    threefry2x32(k0, k1, 0u, 2u, a0, a1);
    threefry2x32(k0, k1, 1u, 3u, b0, b1);
    nk0 = a0; nk1 = b0; sk0 = a1; sk1 = b1;
    k0 = nk0; k1 = nk1;
    // bits via counts iota(8192) paired (i, i+4096)
    for (int i = 0; i < NPTS / 2; ++i) {
      uint32_t o0, o1;
      threefry2x32(sk0, sk1, (uint32_t)i, (uint32_t)(i + NPTS / 2), o0, o1);
      kv[i] = std::make_pair(o0, 0);
      kv[i + NPTS / 2] = std::make_pair(o1, 0);
    }
    for (int i = 0; i < NPTS; ++i) kv[i].second = val[i];
#endif
    std::stable_sort(kv.begin(), kv.end(),
                     [](const std::pair<uint32_t, int>& a,
                        const std::pair<uint32_t, int>& b) { return a.first < b.first; });
    for (int i = 0; i < NPTS; ++i) val[i] = kv[i].second;
  }
  InitIdx ii;
  for (int k = 0; k < KC; ++k) ii.v[k] = val[k];
  return ii;
}

// ---------------- kernels ---------------------------------------------------

// R[b,l,e] = sum_d qk[b,l,d] * W[b,d,e]; 8 rows per block, e = tid.
__global__ void __launch_bounds__(256) k_compute_R(const float* __restrict__ qk,
                                                   const float* __restrict__ W) {
  __shared__ float q[8][DIM];
  const int blk = blockIdx.x;               // 0..1023
  const int b = blk / (LSEQ / 8);
  const int r0 = (blk % (LSEQ / 8)) * 8;
  const int t = threadIdx.x;
  for (int r = 0; r < 8; ++r)
    q[r][t] = qk[((size_t)b * LSEQ + r0 + r) * DIM + t];
  __syncthreads();
  float acc[8] = {0.f, 0.f, 0.f, 0.f, 0.f, 0.f, 0.f, 0.f};
  const float* Wb = W + (size_t)b * DIM * DIM;
  for (int d = 0; d < DIM; ++d) {
    const float w = Wb[d * DIM + t];
#pragma unroll
    for (int r = 0; r < 8; ++r) acc[r] = fmaf(q[r][d], w, acc[r]);
  }
  for (int r = 0; r < 8; ++r)
    g_R[((size_t)b * LSEQ + r0 + r) * DIM + t] = acc[r];
}

// xsq[i] = sum_d R[i,d]^2 (one wave per point, fixed butterfly order)
__global__ void k_xsq() {
  const int i = blockIdx.x;
  const int t = threadIdx.x;  // 64 threads
  const float4 x = *(const float4*)(g_R + (size_t)i * DIM + t * 4);
  float s = x.x * x.x + x.y * x.y + x.z * x.z + x.w * x.w;
  for (int o = 32; o > 0; o >>= 1) s += __shfl_xor(s, o);
  if (t == 0) g_xsq[i] = s;
}

__global__ void __launch_bounds__(256) k_init_cent(InitIdx ii) {
  const int k = blockIdx.x, t = threadIdx.x;
  const float c = g_R[(size_t)ii.v[k] * DIM + t];
  g_cent[k * DIM + t] = c;
  __shared__ float red[256];
  red[t] = c * c;
  __syncthreads();
  for (int o = 128; o > 0; o >>= 1) {
    if (t < o) red[t] += red[t + o];
    __syncthreads();
  }
  if (t == 0) g_csq[k] = red[0];
}

// assign: argmin_k (xsq - 2*dot(X,C_k)) + csq[k], first-min wins. 64 thr/block.
__global__ void __launch_bounds__(64) k_assign() {
  __shared__ float C[KC * DIM];  // 64 KB
  const int t = threadIdx.x;
  for (int j = t; j < KC * DIM; j += 64) C[j] = g_cent[j];
  __syncthreads();
  const int i = blockIdx.x * 64 + t;
  const float* X = g_R + (size_t)i * DIM;
  float acc[KC];
#pragma unroll
  for (int k = 0; k < KC; ++k) acc[k] = 0.f;
  for (int d = 0; d < DIM; d += 4) {
    const float4 x = *(const float4*)(X + d);
#pragma unroll
    for (int k = 0; k < KC; ++k) {
      const float4 c = *(const float4*)(&C[k * DIM + d]);
      acc[k] = fmaf(x.x, c.x, fmaf(x.y, c.y, fmaf(x.z, c.z, fmaf(x.w, c.w, acc[k]))));
    }
  }
  const float xs = g_xsq[i];
  float best = 3.4e38f;
  int bk = 0;
#pragma unroll
  for (int k = 0; k < KC; ++k) {
    const float v = (xs - 2.0f * acc[k]) + g_csq[k];
    if (v < best) { best = v; bk = k; }
  }
  g_idx[i] = bk;
}

// update stage A: per-chunk segment sums (deterministic: sequential points)
__global__ void __launch_bounds__(256) k_upA() {
  __shared__ float acc[KC][DIM];  // exactly 64 KB
  const int c = blockIdx.x, t = threadIdx.x;
  for (int j = t; j < KC * DIM; j += 256) ((float*)acc)[j] = 0.f;
  __syncthreads();
  int cnt = 0;  // thread t<64 counts cluster t
  const int p0 = c * (NPTS / NCHUNK);
  for (int p = p0; p < p0 + (NPTS / NCHUNK); ++p) {
    const int k = g_idx[p];
    acc[k][t] += g_R[(size_t)p * DIM + t];  // thread t owns column t: no race
    if (t == k) cnt++;
  }
  __syncthreads();
  for (int j = t; j < KC * DIM; j += 256) (&g_part[c][0][0])[j] = ((float*)acc)[j];
  if (t < KC) g_pcnt[c][t] = cnt;
}

// update stage B: combine chunks in fixed order, divide, recompute csq
__global__ void __launch_bounds__(256) k_upB() {
  const int k = blockIdx.x, t = threadIdx.x;  // t = dim
  float s = 0.f;
  for (int c = 0; c < NCHUNK; ++c) s += g_part[c][k][t];
  int cnt = 0;
  for (int c = 0; c < NCHUNK; ++c) cnt += g_pcnt[c][k];
  const float oldc = g_cent[k * DIM + t];
  const float nc = (cnt > 0) ? (s / (float)cnt) : oldc;
  g_cent[k * DIM + t] = nc;
  __shared__ float red[256];
  red[t] = nc * nc;
  __syncthreads();
  for (int o = 128; o > 0; o >>= 1) {
    if (t < o) red[t] += red[t + o];
    __syncthreads();
  }
  if (t == 0) g_csq[k] = red[0];
}

// mask write: out[b,h,i,j] = (cid[b,i]==cid[b,j]) ? 0 : -10000. 16 rows/block.
__global__ void __launch_bounds__(256) k_mask(float* __restrict__ out, int H) {
  const int blk = blockIdx.x;
  const int tiles = LSEQ / 16;  // 256
  const int b = blk / (H * tiles);
  const int h = (blk / tiles) % H;
  const int tile = blk % tiles;
  const int t = threadIdx.x;
  __shared__ int cid[LSEQ];  // 16 KB
  for (int j = t; j < LSEQ; j += 256) cid[j] = g_idx[b * LSEQ + j];
  __syncthreads();
  const size_t base = ((size_t)(b * H + h) * LSEQ + (size_t)tile * 16) * LSEQ;
  for (int r = 0; r < 16; ++r) {
    const int my = cid[tile * 16 + r];
    float4* orow = (float4*)(out + base + (size_t)r * LSEQ);
#pragma unroll
    for (int s = 0; s < 4; ++s) {
      const int c4 = s * 256 + t;  // float4 index within row
      const int j = c4 * 4;
      float4 v;
      v.x = (cid[j + 0] == my) ? 0.f : -10000.f;
      v.y = (cid[j + 1] == my) ? 0.f : -10000.f;
      v.z = (cid[j + 2] == my) ? 0.f : -10000.f;
      v.w = (cid[j + 3] == my) ? 0.f : -10000.f;
      orow[c4] = v;
    }
  }
}

// ---------------- launch -----------------------------------------------------
extern "C" void kernel_launch(void* const* d_in, const int* in_sizes, int n_in,
                              void* d_out, int out_size, void* d_ws, size_t ws_size,
                              hipStream_t stream) {
  const float* qk = (const float*)d_in[0];
  const float* W = (const float*)d_in[1];
  const int H = out_size / (NB * LSEQ * LSEQ);  // 8

  const InitIdx ii = compute_init_indices();  // pure host integer math, deterministic

  k_compute_R<<<NB * (LSEQ / 8), 256, 0, stream>>>(qk, W);
  k_xsq<<<NPTS, 64, 0, stream>>>();
  k_init_cent<<<KC, 256, 0, stream>>>(ii);
  for (int it = 0; it < KM_ITERS; ++it) {
    k_assign<<<NPTS / 64, 64, 0, stream>>>();
    k_upA<<<NCHUNK, 256, 0, stream>>>();
    k_upB<<<KC, 256, 0, stream>>>();
  }
  k_assign<<<NPTS / 64, 64, 0, stream>>>();  // final assignment -> cid
  k_mask<<<NB * H * (LSEQ / 16), 256, 0, stream>>>((float*)d_out, H);
}

// Round 2
// 1281.778 us; speedup vs baseline: 1.2931x; 1.2931x over previous
//
#include <hip/hip_runtime.h>
#include <stdint.h>
#include <stddef.h>
#include <vector>
#include <algorithm>
#include <utility>

// Problem constants (B=2, L=4096, D=256, H=8, K=sqrt(L)=64, 10 Lloyd iters)
#define NPTS 8192
#define DIM  256
#define KC   64
#define LSEQ 4096
#define NB   2
#define KM_ITERS 10
#define NCHUNK 64   // 8192/128 points per chunk
#define XPITCH 260  // padded LDS row for X tile (breaks bank aliasing)

// JAX threefry mode: 1 = partitionable (default since jax 0.4.36), 0 = original
#define JAX_THREEFRY_PARTITIONABLE 1

// ---------------- static device scratch (fully rewritten every call) --------
__device__ float g_R[NPTS * DIM];          // 8 MB   rotated points
__device__ float g_xsq[NPTS];              // 32 KB  per-point squared norm
__device__ float g_cent[KC * DIM];         // 64 KB  centroids
__device__ float g_csq[KC];                // per-centroid squared norm
__device__ int   g_idx[NPTS];              // assignments (final = cid)
__device__ float g_part[NCHUNK][KC][DIM];  // 4 MB   chunked segment sums
__device__ int   g_pcnt[NCHUNK][KC];       // chunked counts

// ---------------- host threefry2x32 (exact JAX semantics) -------------------
static inline uint32_t rotl32(uint32_t x, int r) { return (x << r) | (x >> (32 - r)); }

static void threefry2x32(uint32_t k0, uint32_t k1, uint32_t x0, uint32_t x1,
                         uint32_t& o0, uint32_t& o1) {
  const uint32_t ks0 = k0, ks1 = k1, ks2 = k0 ^ k1 ^ 0x1BD11BDAu;
  const int r1[4] = {13, 15, 26, 6}, r2[4] = {17, 29, 16, 24};
  x0 += ks0; x1 += ks1;
  for (int i = 0; i < 4; ++i) { x0 += x1; x1 = rotl32(x1, r1[i]); x1 ^= x0; }
  x0 += ks1; x1 += ks2 + 1u;
  for (int i = 0; i < 4; ++i) { x0 += x1; x1 = rotl32(x1, r2[i]); x1 ^= x0; }
  x0 += ks2; x1 += ks0 + 2u;
  for (int i = 0; i < 4; ++i) { x0 += x1; x1 = rotl32(x1, r1[i]); x1 ^= x0; }
  x0 += ks0; x1 += ks1 + 3u;
  for (int i = 0; i < 4; ++i) { x0 += x1; x1 = rotl32(x1, r2[i]); x1 ^= x0; }
  x0 += ks1; x1 += ks2 + 4u;
  for (int i = 0; i < 4; ++i) { x0 += x1; x1 = rotl32(x1, r1[i]); x1 ^= x0; }
  x0 += ks2; x1 += ks0 + 5u;
  o0 = x0; o1 = x1;
}

struct InitIdx { int v[KC]; };

// jax.random.choice(key(42), 8192, (64,), replace=False)
//  = permutation(key, arange(8192))[:64]  (2-round threefry shuffle)
static InitIdx compute_init_indices() {
  uint32_t k0 = 0u, k1 = 42u;  // jax.random.key(42) -> [0, 42]
  std::vector<int> val(NPTS);
  for (int i = 0; i < NPTS; ++i) val[i] = i;
  std::vector<std::pair<uint32_t, int>> kv(NPTS);
  for (int round = 0; round < 2; ++round) {
    uint32_t nk0, nk1, sk0, sk1;
#if JAX_THREEFRY_PARTITIONABLE
    threefry2x32(k0, k1, 0u, 0u, nk0, nk1);
    threefry2x32(k0, k1, 0u, 1u, sk0, sk1);
    k0 = nk0; k1 = nk1;
    for (int i = 0; i < NPTS; ++i) {
      uint32_t o0, o1;
      threefry2x32(sk0, sk1, 0u, (uint32_t)i, o0, o1);
      kv[i] = std::make_pair(o0 ^ o1, val[i]);
    }
#else
    uint32_t a0, a1, b0, b1;
    threefry2x32(k0, k1, 0u, 2u, a0, a1);
    threefry2x32(k0, k1, 1u, 3u, b0, b1);
    nk0 = a0; nk1 = b0; sk0 = a1; sk1 = b1;
    k0 = nk0; k1 = nk1;
    for (int i = 0; i < NPTS / 2; ++i) {
      uint32_t o0, o1;
      threefry2x32(sk0, sk1, (uint32_t)i, (uint32_t)(i + NPTS / 2), o0, o1);
      kv[i] = std::make_pair(o0, 0);
      kv[i + NPTS / 2] = std::make_pair(o1, 0);
    }
    for (int i = 0; i < NPTS; ++i) kv[i].second = val[i];
#endif
    std::stable_sort(kv.begin(), kv.end(),
                     [](const std::pair<uint32_t, int>& a,
                        const std::pair<uint32_t, int>& b) { return a.first < b.first; });
    for (int i = 0; i < NPTS; ++i) val[i] = kv[i].second;
  }
  InitIdx ii;
  for (int k = 0; k < KC; ++k) ii.v[k] = val[k];
  return ii;
}

// ---------------- kernels ---------------------------------------------------

// R[b,l,e] = sum_d qk[b,l,d] * W[b,d,e]; 8 rows per block, e = tid.
__global__ void __launch_bounds__(256) k_compute_R(const float* __restrict__ qk,
                                                   const float* __restrict__ W) {
  __shared__ float q[8][DIM];
  const int blk = blockIdx.x;               // 0..1023
  const int b = blk / (LSEQ / 8);
  const int r0 = (blk % (LSEQ / 8)) * 8;
  const int t = threadIdx.x;
  for (int r = 0; r < 8; ++r)
    q[r][t] = qk[((size_t)b * LSEQ + r0 + r) * DIM + t];
  __syncthreads();
  float acc[8] = {0.f, 0.f, 0.f, 0.f, 0.f, 0.f, 0.f, 0.f};
  const float* Wb = W + (size_t)b * DIM * DIM;
  for (int d = 0; d < DIM; ++d) {
    const float w = Wb[d * DIM + t];
#pragma unroll
    for (int r = 0; r < 8; ++r) acc[r] = fmaf(q[r][d], w, acc[r]);
  }
  for (int r = 0; r < 8; ++r)
    g_R[((size_t)b * LSEQ + r0 + r) * DIM + t] = acc[r];
}

// xsq[i] = sum_d R[i,d]^2 (one wave per point, fixed butterfly order)
__global__ void k_xsq() {
  const int i = blockIdx.x;
  const int t = threadIdx.x;  // 64 threads
  const float4 x = *(const float4*)(g_R + (size_t)i * DIM + t * 4);
  float s = x.x * x.x + x.y * x.y + x.z * x.z + x.w * x.w;
  for (int o = 32; o > 0; o >>= 1) s += __shfl_xor(s, o);
  if (t == 0) g_xsq[i] = s;
}

__global__ void __launch_bounds__(256) k_init_cent(InitIdx ii) {
  const int k = blockIdx.x, t = threadIdx.x;
  const float c = g_R[(size_t)ii.v[k] * DIM + t];
  g_cent[k * DIM + t] = c;
  __shared__ float red[256];
  red[t] = c * c;
  __syncthreads();
  for (int o = 128; o > 0; o >>= 1) {
    if (t < o) red[t] += red[t + o];
    __syncthreads();
  }
  if (t == 0) g_csq[k] = red[0];
}

// assign (tiled): 64 points x 64 clusters per block, 4x4 per thread.
// Dot products use the EXACT same d-ascending nested-fmaf chain as the
// original one-thread-per-point version -> bitwise-identical distances.
__global__ void __launch_bounds__(256) k_assign() {
  __shared__ float Xs[64 * XPITCH];   // 66,560 B (padded rows: conflict-free)
  __shared__ float Cs[DIM * KC];      // 65,536 B transposed Cs[d][k]
  const int t = threadIdx.x;
  const int p0 = blockIdx.x * 64;

  // load X tile (coalesced global, linear LDS)
  for (int idx = t; idx < 64 * DIM; idx += 256) {
    const int r = idx >> 8;          // point row 0..63
    const int cdim = idx & 255;
    Xs[r * XPITCH + cdim] = g_R[(size_t)(p0 + r) * DIM + cdim];
  }
  // load C transposed: lane k = idx&63 -> LDS writes conflict-free (2-way)
  for (int idx = t; idx < KC * DIM; idx += 256) {
    const int k = idx & 63;
    const int d = idx >> 6;
    Cs[d * 64 + k] = g_cent[k * DIM + d];
  }
  __syncthreads();

  const int ptg = t >> 4;            // 0..15 -> points 4*ptg..4*ptg+3
  const int ctg = t & 15;            // 0..15 -> clusters 4*ctg..4*ctg+3
  const int ct = ctg * 4;

  float acc[4][4];
#pragma unroll
  for (int r = 0; r < 4; ++r)
#pragma unroll
    for (int j = 0; j < 4; ++j) acc[r][j] = 0.f;

#pragma unroll 4
  for (int d = 0; d < DIM; d += 4) {
    const float4 cv0 = *(const float4*)&Cs[(d + 0) * 64 + ct];
    const float4 cv1 = *(const float4*)&Cs[(d + 1) * 64 + ct];
    const float4 cv2 = *(const float4*)&Cs[(d + 2) * 64 + ct];
    const float4 cv3 = *(const float4*)&Cs[(d + 3) * 64 + ct];
#pragma unroll
    for (int r = 0; r < 4; ++r) {
      const float4 x = *(const float4*)&Xs[(ptg * 4 + r) * XPITCH + d];
      acc[r][0] = fmaf(x.x, cv0.x, fmaf(x.y, cv1.x, fmaf(x.z, cv2.x, fmaf(x.w, cv3.x, acc[r][0]))));
      acc[r][1] = fmaf(x.x, cv0.y, fmaf(x.y, cv1.y, fmaf(x.z, cv2.y, fmaf(x.w, cv3.y, acc[r][1]))));
      acc[r][2] = fmaf(x.x, cv0.z, fmaf(x.y, cv1.z, fmaf(x.z, cv2.z, fmaf(x.w, cv3.z, acc[r][2]))));
      acc[r][3] = fmaf(x.x, cv0.w, fmaf(x.y, cv1.w, fmaf(x.z, cv2.w, fmaf(x.w, cv3.w, acc[r][3]))));
    }
  }

  const float cs0 = g_csq[ct + 0], cs1 = g_csq[ct + 1];
  const float cs2 = g_csq[ct + 2], cs3 = g_csq[ct + 3];
#pragma unroll
  for (int r = 0; r < 4; ++r) {
    const int p = p0 + ptg * 4 + r;
    const float xs = g_xsq[p];
    float best = 3.4e38f;
    int bk = 0;
    {
      float v;
      v = (xs - 2.0f * acc[r][0]) + cs0; if (v < best) { best = v; bk = ct + 0; }
      v = (xs - 2.0f * acc[r][1]) + cs1; if (v < best) { best = v; bk = ct + 1; }
      v = (xs - 2.0f * acc[r][2]) + cs2; if (v < best) { best = v; bk = ct + 2; }
      v = (xs - 2.0f * acc[r][3]) + cs3; if (v < best) { best = v; bk = ct + 3; }
    }
    // reduce over the 16 lanes of this point-group: min v, lowest k on ties
#pragma unroll
    for (int o = 1; o < 16; o <<= 1) {
      const float ov = __shfl_xor(best, o);
      const int obk = __shfl_xor(bk, o);
      if (ov < best || (ov == best && obk < bk)) { best = ov; bk = obk; }
    }
    if (ctg == 0) g_idx[p] = bk;
  }
}

// update stage A: thread = (cluster, dim-quad-group); register accumulate over
// the chunk's points in ascending p order (bitwise-identical per-(k,dim) sums
// to the original sequential LDS version).
__global__ void __launch_bounds__(256) k_upA() {
  const int c = blockIdx.x;            // chunk
  const int t = threadIdx.x;
  const int k = t >> 2;                // cluster 0..63
  const int dg = t & 3;                // dims dg*64 .. dg*64+63
  float4 s[16];
#pragma unroll
  for (int q = 0; q < 16; ++q) s[q] = make_float4(0.f, 0.f, 0.f, 0.f);
  int cnt = 0;
  const int p0 = c * (NPTS / NCHUNK);
  for (int p = p0; p < p0 + (NPTS / NCHUNK); ++p) {
    const int kp = g_idx[p];
    if (kp == k) {
      const float4* row = (const float4*)(g_R + (size_t)p * DIM + dg * 64);
#pragma unroll
      for (int q = 0; q < 16; ++q) {
        const float4 x = row[q];
        s[q].x += x.x; s[q].y += x.y; s[q].z += x.z; s[q].w += x.w;
      }
      cnt++;
    }
  }
  float4* out = (float4*)(&g_part[c][k][dg * 64]);
#pragma unroll
  for (int q = 0; q < 16; ++q) out[q] = s[q];
  if (dg == 0) g_pcnt[c][k] = cnt;
}

// update stage B: combine chunks in fixed order, divide, recompute csq
__global__ void __launch_bounds__(256) k_upB() {
  const int k = blockIdx.x, t = threadIdx.x;  // t = dim
  float s = 0.f;
  for (int c = 0; c < NCHUNK; ++c) s += g_part[c][k][t];
  int cnt = 0;
  for (int c = 0; c < NCHUNK; ++c) cnt += g_pcnt[c][k];
  const float oldc = g_cent[k * DIM + t];
  const float nc = (cnt > 0) ? (s / (float)cnt) : oldc;
  g_cent[k * DIM + t] = nc;
  __shared__ float red[256];
  red[t] = nc * nc;
  __syncthreads();
  for (int o = 128; o > 0; o >>= 1) {
    if (t < o) red[t] += red[t + o];
    __syncthreads();
  }
  if (t == 0) g_csq[k] = red[0];
}

// mask write: out[b,h,i,j] = (cid[b,i]==cid[b,j]) ? 0 : -10000. 16 rows/block.
__global__ void __launch_bounds__(256) k_mask(float* __restrict__ out, int H) {
  const int blk = blockIdx.x;
  const int tiles = LSEQ / 16;  // 256
  const int b = blk / (H * tiles);
  const int h = (blk / tiles) % H;
  const int tile = blk % tiles;
  const int t = threadIdx.x;
  __shared__ int cid[LSEQ];  // 16 KB
  for (int j = t; j < LSEQ; j += 256) cid[j] = g_idx[b * LSEQ + j];
  __syncthreads();
  const size_t base = ((size_t)(b * H + h) * LSEQ + (size_t)tile * 16) * LSEQ;
  for (int r = 0; r < 16; ++r) {
    const int my = cid[tile * 16 + r];
    float4* orow = (float4*)(out + base + (size_t)r * LSEQ);
#pragma unroll
    for (int s = 0; s < 4; ++s) {
      const int c4 = s * 256 + t;  // float4 index within row
      const int j = c4 * 4;
      float4 v;
      v.x = (cid[j + 0] == my) ? 0.f : -10000.f;
      v.y = (cid[j + 1] == my) ? 0.f : -10000.f;
      v.z = (cid[j + 2] == my) ? 0.f : -10000.f;
      v.w = (cid[j + 3] == my) ? 0.f : -10000.f;
      orow[c4] = v;
    }
  }
}

// ---------------- launch -----------------------------------------------------
extern "C" void kernel_launch(void* const* d_in, const int* in_sizes, int n_in,
                              void* d_out, int out_size, void* d_ws, size_t ws_size,
                              hipStream_t stream) {
  const float* qk = (const float*)d_in[0];
  const float* W = (const float*)d_in[1];
  const int H = out_size / (NB * LSEQ * LSEQ);  // 8

  const InitIdx ii = compute_init_indices();  // pure host integer math

  k_compute_R<<<NB * (LSEQ / 8), 256, 0, stream>>>(qk, W);
  k_xsq<<<NPTS, 64, 0, stream>>>();
  k_init_cent<<<KC, 256, 0, stream>>>(ii);
  for (int it = 0; it < KM_ITERS; ++it) {
    k_assign<<<NPTS / 64, 256, 0, stream>>>();
    k_upA<<<NCHUNK, 256, 0, stream>>>();
    k_upB<<<KC, 256, 0, stream>>>();
  }
  k_assign<<<NPTS / 64, 256, 0, stream>>>();  // final assignment -> cid
  k_mask<<<NB * H * (LSEQ / 16), 256, 0, stream>>>((float*)d_out, H);
}

// Round 3
// 962.728 us; speedup vs baseline: 1.7217x; 1.3314x over previous
//
#include <hip/hip_runtime.h>
#include <stdint.h>
#include <stddef.h>
#include <vector>
#include <algorithm>
#include <utility>

// Problem constants (B=2, L=4096, D=256, H=8, K=sqrt(L)=64, 10 Lloyd iters)
#define NPTS 8192
#define DIM  256
#define KC   64
#define LSEQ 4096
#define NB   2
#define KM_ITERS 10
#define NCHUNK 64   // 8192/128 points per chunk
#define XPITCH 260  // padded LDS row for X tile (breaks bank aliasing)

// JAX threefry mode: 1 = partitionable (default since jax 0.4.36), 0 = original
#define JAX_THREEFRY_PARTITIONABLE 1

// ---------------- static device scratch (fully rewritten every call) --------
__device__ float g_R[NPTS * DIM];          // 8 MB   rotated points
__device__ float g_xsq[NPTS];              // 32 KB  per-point squared norm
__device__ float g_cent[KC * DIM];         // 64 KB  centroids
__device__ float g_csq[KC];                // per-centroid squared norm
__device__ int   g_idx[NPTS];              // final assignments (= cid)
__device__ float g_part[NCHUNK][KC][DIM];  // 4 MB   chunked segment sums
__device__ int   g_pcnt[NCHUNK][KC];       // chunked counts

// ---------------- host threefry2x32 (exact JAX semantics) -------------------
static inline uint32_t rotl32(uint32_t x, int r) { return (x << r) | (x >> (32 - r)); }

static void threefry2x32(uint32_t k0, uint32_t k1, uint32_t x0, uint32_t x1,
                         uint32_t& o0, uint32_t& o1) {
  const uint32_t ks0 = k0, ks1 = k1, ks2 = k0 ^ k1 ^ 0x1BD11BDAu;
  const int r1[4] = {13, 15, 26, 6}, r2[4] = {17, 29, 16, 24};
  x0 += ks0; x1 += ks1;
  for (int i = 0; i < 4; ++i) { x0 += x1; x1 = rotl32(x1, r1[i]); x1 ^= x0; }
  x0 += ks1; x1 += ks2 + 1u;
  for (int i = 0; i < 4; ++i) { x0 += x1; x1 = rotl32(x1, r2[i]); x1 ^= x0; }
  x0 += ks2; x1 += ks0 + 2u;
  for (int i = 0; i < 4; ++i) { x0 += x1; x1 = rotl32(x1, r1[i]); x1 ^= x0; }
  x0 += ks0; x1 += ks1 + 3u;
  for (int i = 0; i < 4; ++i) { x0 += x1; x1 = rotl32(x1, r2[i]); x1 ^= x0; }
  x0 += ks1; x1 += ks2 + 4u;
  for (int i = 0; i < 4; ++i) { x0 += x1; x1 = rotl32(x1, r1[i]); x1 ^= x0; }
  x0 += ks2; x1 += ks0 + 5u;
  o0 = x0; o1 = x1;
}

struct InitIdx { int v[KC]; };

// jax.random.choice(key(42), 8192, (64,), replace=False)
//  = permutation(key, arange(8192))[:64]  (2-round threefry shuffle)
static InitIdx compute_init_indices() {
  uint32_t k0 = 0u, k1 = 42u;  // jax.random.key(42) -> [0, 42]
  std::vector<int> val(NPTS);
  for (int i = 0; i < NPTS; ++i) val[i] = i;
  std::vector<std::pair<uint32_t, int>> kv(NPTS);
  for (int round = 0; round < 2; ++round) {
    uint32_t nk0, nk1, sk0, sk1;
#if JAX_THREEFRY_PARTITIONABLE
    threefry2x32(k0, k1, 0u, 0u, nk0, nk1);
    threefry2x32(k0, k1, 0u, 1u, sk0, sk1);
    k0 = nk0; k1 = nk1;
    for (int i = 0; i < NPTS; ++i) {
      uint32_t o0, o1;
      threefry2x32(sk0, sk1, 0u, (uint32_t)i, o0, o1);
      kv[i] = std::make_pair(o0 ^ o1, val[i]);
    }
#else
    uint32_t a0, a1, b0, b1;
    threefry2x32(k0, k1, 0u, 2u, a0, a1);
    threefry2x32(k0, k1, 1u, 3u, b0, b1);
    nk0 = a0; nk1 = b0; sk0 = a1; sk1 = b1;
    k0 = nk0; k1 = nk1;
    for (int i = 0; i < NPTS / 2; ++i) {
      uint32_t o0, o1;
      threefry2x32(sk0, sk1, (uint32_t)i, (uint32_t)(i + NPTS / 2), o0, o1);
      kv[i] = std::make_pair(o0, 0);
      kv[i + NPTS / 2] = std::make_pair(o1, 0);
    }
    for (int i = 0; i < NPTS; ++i) kv[i].second = val[i];
#endif
    std::stable_sort(kv.begin(), kv.end(),
                     [](const std::pair<uint32_t, int>& a,
                        const std::pair<uint32_t, int>& b) { return a.first < b.first; });
    for (int i = 0; i < NPTS; ++i) val[i] = kv[i].second;
  }
  InitIdx ii;
  for (int k = 0; k < KC; ++k) ii.v[k] = val[k];
  return ii;
}

// ---------------- kernels ---------------------------------------------------

// Fused R-GEMM + xsq. R[b,l,e] = sum_d qk[b,l,d]*W[b,d,e]; 8 rows per block.
// xsq uses the EXACT original chain: per-lane float4 square-sum over dims
// 4t..4t+3, then 64-lane __shfl_xor butterfly (32,16,8,4,2,1).
__global__ void __launch_bounds__(256) k_R_xsq(const float* __restrict__ qk,
                                               const float* __restrict__ W) {
  __shared__ float q[8][DIM];
  const int blk = blockIdx.x;               // 0..1023
  const int b = blk / (LSEQ / 8);
  const int r0 = (blk % (LSEQ / 8)) * 8;
  const int t = threadIdx.x;
  for (int r = 0; r < 8; ++r)
    q[r][t] = qk[((size_t)b * LSEQ + r0 + r) * DIM + t];
  __syncthreads();
  float acc[8] = {0.f, 0.f, 0.f, 0.f, 0.f, 0.f, 0.f, 0.f};
  const float* Wb = W + (size_t)b * DIM * DIM;
  for (int d = 0; d < DIM; ++d) {
    const float w = Wb[d * DIM + t];
#pragma unroll
    for (int r = 0; r < 8; ++r) acc[r] = fmaf(q[r][d], w, acc[r]);
  }
  for (int r = 0; r < 8; ++r)
    g_R[((size_t)b * LSEQ + r0 + r) * DIM + t] = acc[r];
  __syncthreads();  // all q reads done -> safe to overwrite
  for (int r = 0; r < 8; ++r) q[r][t] = acc[r];
  __syncthreads();
  // wave w handles rows 2w, 2w+1 with the original 64-lane chain
  const int w = t >> 6, lane = t & 63;
#pragma unroll
  for (int rr = 0; rr < 2; ++rr) {
    const int r = w * 2 + rr;
    const float4 x = *(const float4*)&q[r][lane * 4];
    float s = x.x * x.x + x.y * x.y + x.z * x.z + x.w * x.w;
    for (int o = 32; o > 0; o >>= 1) s += __shfl_xor(s, o);
    if (lane == 0) g_xsq[(size_t)b * LSEQ + r0 + r] = s;
  }
}

__global__ void __launch_bounds__(256) k_init_cent(InitIdx ii) {
  const int k = blockIdx.x, t = threadIdx.x;
  const float c = g_R[(size_t)ii.v[k] * DIM + t];
  g_cent[k * DIM + t] = c;
  __shared__ float red[256];
  red[t] = c * c;
  __syncthreads();
  for (int o = 128; o > 0; o >>= 1) {
    if (t < o) red[t] += red[t + o];
    __syncthreads();
  }
  if (t == 0) g_csq[k] = red[0];
}

// Fused assign + upA: block = chunk of 128 points. Assign runs in two 64-point
// halves (same 16x16 thread-tile, same d-ascending nested-fmaf chains as
// before -> bitwise-identical distances). Assignments stay in LDS; upA sums
// ascending p with the identical register chain.
__global__ void __launch_bounds__(256) k_iter(int write_idx, int do_upA) {
  __shared__ float Cs[DIM * KC];      // 64 KB transposed Cs[d][k]
  __shared__ float Xs[64 * XPITCH];   // 66.56 KB (padded rows)
  __shared__ int idx_s[128];
  const int t = threadIdx.x;
  const int c = blockIdx.x;           // chunk 0..63
  const int p0 = c * 128;

  // load C transposed (gather-global, conflict-free LDS writes) — as round 2
  for (int idx = t; idx < KC * DIM; idx += 256) {
    const int k = idx & 63;
    const int d = idx >> 6;
    Cs[d * 64 + k] = g_cent[k * DIM + d];
  }

  const int ptg = t >> 4;             // 0..15 -> 4-point group
  const int ctg = t & 15;             // 0..15 -> 4-cluster group
  const int ct = ctg * 4;

  for (int h = 0; h < 2; ++h) {
    __syncthreads();  // protect Xs reuse (and cover Cs load on h==0)
    for (int idx = t; idx < 64 * DIM; idx += 256) {
      const int r = idx >> 8;
      const int d = idx & 255;
      Xs[r * XPITCH + d] = g_R[(size_t)(p0 + h * 64 + r) * DIM + d];
    }
    __syncthreads();

    float acc[4][4];
#pragma unroll
    for (int r = 0; r < 4; ++r)
#pragma unroll
      for (int j = 0; j < 4; ++j) acc[r][j] = 0.f;

#pragma unroll 4
    for (int d = 0; d < DIM; d += 4) {
      const float4 cv0 = *(const float4*)&Cs[(d + 0) * 64 + ct];
      const float4 cv1 = *(const float4*)&Cs[(d + 1) * 64 + ct];
      const float4 cv2 = *(const float4*)&Cs[(d + 2) * 64 + ct];
      const float4 cv3 = *(const float4*)&Cs[(d + 3) * 64 + ct];
#pragma unroll
      for (int r = 0; r < 4; ++r) {
        const float4 x = *(const float4*)&Xs[(ptg * 4 + r) * XPITCH + d];
        acc[r][0] = fmaf(x.x, cv0.x, fmaf(x.y, cv1.x, fmaf(x.z, cv2.x, fmaf(x.w, cv3.x, acc[r][0]))));
        acc[r][1] = fmaf(x.x, cv0.y, fmaf(x.y, cv1.y, fmaf(x.z, cv2.y, fmaf(x.w, cv3.y, acc[r][1]))));
        acc[r][2] = fmaf(x.x, cv0.z, fmaf(x.y, cv1.z, fmaf(x.z, cv2.z, fmaf(x.w, cv3.z, acc[r][2]))));
        acc[r][3] = fmaf(x.x, cv0.w, fmaf(x.y, cv1.w, fmaf(x.z, cv2.w, fmaf(x.w, cv3.w, acc[r][3]))));
      }
    }

    const float cs0 = g_csq[ct + 0], cs1 = g_csq[ct + 1];
    const float cs2 = g_csq[ct + 2], cs3 = g_csq[ct + 3];
#pragma unroll
    for (int r = 0; r < 4; ++r) {
      const int pl = h * 64 + ptg * 4 + r;
      const float xs = g_xsq[p0 + pl];
      float best = 3.4e38f;
      int bk = 0;
      {
        float v;
        v = (xs - 2.0f * acc[r][0]) + cs0; if (v < best) { best = v; bk = ct + 0; }
        v = (xs - 2.0f * acc[r][1]) + cs1; if (v < best) { best = v; bk = ct + 1; }
        v = (xs - 2.0f * acc[r][2]) + cs2; if (v < best) { best = v; bk = ct + 2; }
        v = (xs - 2.0f * acc[r][3]) + cs3; if (v < best) { best = v; bk = ct + 3; }
      }
#pragma unroll
      for (int o = 1; o < 16; o <<= 1) {
        const float ov = __shfl_xor(best, o);
        const int obk = __shfl_xor(bk, o);
        if (ov < best || (ov == best && obk < bk)) { best = ov; bk = obk; }
      }
      if (ctg == 0) {
        idx_s[pl] = bk;
        if (write_idx) g_idx[p0 + pl] = bk;
      }
    }
  }

  if (do_upA) {
    __syncthreads();
    const int k = t >> 2;   // cluster 0..63
    const int dg = t & 3;   // dims dg*64 .. dg*64+63
    float4 s[16];
#pragma unroll
    for (int q = 0; q < 16; ++q) s[q] = make_float4(0.f, 0.f, 0.f, 0.f);
    int cnt = 0;
    // pl 0..63: rows from global (L2-hot); pl 64..127: rows still in Xs.
    // Same values, same ascending order -> bit-identical sums.
    for (int pl = 0; pl < 64; ++pl) {
      if (idx_s[pl] == k) {
        const float4* row = (const float4*)(g_R + (size_t)(p0 + pl) * DIM + dg * 64);
#pragma unroll
        for (int q = 0; q < 16; ++q) {
          const float4 x = row[q];
          s[q].x += x.x; s[q].y += x.y; s[q].z += x.z; s[q].w += x.w;
        }
        cnt++;
      }
    }
    for (int pl = 64; pl < 128; ++pl) {
      if (idx_s[pl] == k) {
        const float4* row = (const float4*)(&Xs[(pl - 64) * XPITCH + dg * 64]);
#pragma unroll
        for (int q = 0; q < 16; ++q) {
          const float4 x = row[q];
          s[q].x += x.x; s[q].y += x.y; s[q].z += x.z; s[q].w += x.w;
        }
        cnt++;
      }
    }
    float4* out = (float4*)(&g_part[c][k][dg * 64]);
#pragma unroll
    for (int q = 0; q < 16; ++q) out[q] = s[q];
    if (dg == 0) g_pcnt[c][k] = cnt;
  }
}

// update stage B: combine chunks in fixed ascending order, divide, csq tree
__global__ void __launch_bounds__(256) k_upB() {
  const int k = blockIdx.x, t = threadIdx.x;  // t = dim
  float s = 0.f;
#pragma unroll 4
  for (int c = 0; c < NCHUNK; ++c) s += g_part[c][k][t];
  int cnt = 0;
#pragma unroll 4
  for (int c = 0; c < NCHUNK; ++c) cnt += g_pcnt[c][k];
  const float oldc = g_cent[k * DIM + t];
  const float nc = (cnt > 0) ? (s / (float)cnt) : oldc;
  g_cent[k * DIM + t] = nc;
  __shared__ float red[256];
  red[t] = nc * nc;
  __syncthreads();
  for (int o = 128; o > 0; o >>= 1) {
    if (t < o) red[t] += red[t + o];
    __syncthreads();
  }
  if (t == 0) g_csq[k] = red[0];
}

// mask write: out[b,h,i,j] = (cid[b,i]==cid[b,j]) ? 0 : -10000. 16 rows/block.
__global__ void __launch_bounds__(256) k_mask(float* __restrict__ out, int H) {
  const int blk = blockIdx.x;
  const int tiles = LSEQ / 16;  // 256
  const int b = blk / (H * tiles);
  const int h = (blk / tiles) % H;
  const int tile = blk % tiles;
  const int t = threadIdx.x;
  __shared__ int cid[LSEQ];  // 16 KB
  for (int j = t; j < LSEQ; j += 256) cid[j] = g_idx[b * LSEQ + j];
  __syncthreads();
  const size_t base = ((size_t)(b * H + h) * LSEQ + (size_t)tile * 16) * LSEQ;
  for (int r = 0; r < 16; ++r) {
    const int my = cid[tile * 16 + r];
    float4* orow = (float4*)(out + base + (size_t)r * LSEQ);
#pragma unroll
    for (int s = 0; s < 4; ++s) {
      const int c4 = s * 256 + t;  // float4 index within row
      const int j = c4 * 4;
      float4 v;
      v.x = (cid[j + 0] == my) ? 0.f : -10000.f;
      v.y = (cid[j + 1] == my) ? 0.f : -10000.f;
      v.z = (cid[j + 2] == my) ? 0.f : -10000.f;
      v.w = (cid[j + 3] == my) ? 0.f : -10000.f;
      orow[c4] = v;
    }
  }
}

// ---------------- launch -----------------------------------------------------
extern "C" void kernel_launch(void* const* d_in, const int* in_sizes, int n_in,
                              void* d_out, int out_size, void* d_ws, size_t ws_size,
                              hipStream_t stream) {
  const float* qk = (const float*)d_in[0];
  const float* W = (const float*)d_in[1];
  const int H = out_size / (NB * LSEQ * LSEQ);  // 8

  const InitIdx ii = compute_init_indices();  // pure host integer math

  k_R_xsq<<<NB * (LSEQ / 8), 256, 0, stream>>>(qk, W);
  k_init_cent<<<KC, 256, 0, stream>>>(ii);
  for (int it = 0; it < KM_ITERS; ++it) {
    k_iter<<<NCHUNK, 256, 0, stream>>>(0, 1);
    k_upB<<<KC, 256, 0, stream>>>();
  }
  k_iter<<<NCHUNK, 256, 0, stream>>>(1, 0);  // final assignment -> cid
  k_mask<<<NB * H * (LSEQ / 16), 256, 0, stream>>>((float*)d_out, H);
}